// Round 3
// baseline (434.888 us; speedup 1.0000x reference)
//
#include <hip/hip_runtime.h>

#define DIM_IN 256
#define DIM_H  64
#define SEQ_LEN 512
#define TPB 4   // row-tiles (64 rows each) per prepass block

typedef _Float16 h2_t  __attribute__((ext_vector_type(2)));
typedef _Float16 h8_t  __attribute__((ext_vector_type(8)));
typedef float    f32x4 __attribute__((ext_vector_type(4)));
union H8 { h8_t v; h2_t p[4]; };

// addrspace(1) pointers: loads/stores emit global_* (vmcnt-only), never flat_*.
typedef const __attribute__((address_space(1))) unsigned* gcu32_p;
typedef const __attribute__((address_space(1))) _Float16* gch16_p;
typedef const __attribute__((address_space(1))) float*    gcf32_p;
typedef       __attribute__((address_space(1))) float*    gf32_p;

__device__ inline float dot2(h2_t a, h2_t b, float c) {
#if __has_builtin(__builtin_amdgcn_fdot2)
    return __builtin_amdgcn_fdot2(a, b, c, false);
#else
    return c + (float)a[0] * (float)b[0] + (float)a[1] * (float)b[1];
#endif
}
__device__ inline float exp2_(float x) {
#if __has_builtin(__builtin_amdgcn_exp2f)
    return __builtin_amdgcn_exp2f(x);
#else
    return exp2f(x);
#endif
}
__device__ inline float rcp_(float x) {
#if __has_builtin(__builtin_amdgcn_rcpf)
    return __builtin_amdgcn_rcpf(x);
#else
    return __fdividef(1.f, x);
#endif
}

// ---------------------------------------------------------------------------
// Pass 1 (MFMA): x-projections, weights amortized over TPB tiles, X tile
// double-buffered through registers. Outputs pre-scaled for exp2 gates:
//   xur.x = -log2(e)*(xu+bu), xur.y = -log2(e)*(xr+br)   (packed f16x2)
//   xi    =  2*log2(e)*(xi+bi)   (f16 into ws if it fits, else f32 into out)
// Unchanged from R2 (prepass time is invariant across 3 structural variants).
// ---------------------------------------------------------------------------
template <int XI16>
__global__ __launch_bounds__(256, 2)
void gru_prepass_mfma(const float* __restrict__ X,
                      const float* __restrict__ W_input,  const float* __restrict__ b_input,
                      const float* __restrict__ W_update, const float* __restrict__ b_update,
                      const float* __restrict__ W_reset,  const float* __restrict__ b_reset,
                      unsigned* __restrict__ xur_out,
                      _Float16* __restrict__ xi16_out, float* __restrict__ xi32_out)
{
    const int tid  = threadIdx.x;
    const int lane = tid & 63;
    const int wv   = tid >> 6;
    const int q    = lane >> 4;
    const int m16  = lane & 15;

    constexpr int LDK = DIM_IN + 8;
    __shared__ _Float16 xs[64 * LDK];

    const int c = wv * 16 + m16;
    h8_t bu[8], brf[8], bif[8];
#pragma unroll
    for (int kt = 0; kt < 8; ++kt) {
        h8_t u, r, i;
#pragma unroll
        for (int jj = 0; jj < 8; ++jj) {
            const int k = kt * 32 + q * 8 + jj;
            u[jj] = (_Float16)W_update[k * DIM_H + c];
            r[jj] = (_Float16)W_reset [k * DIM_H + c];
            i[jj] = (_Float16)W_input [k * DIM_H + c];
        }
        bu[kt] = u; brf[kt] = r; bif[kt] = i;
    }
    const float bzc = b_update[c], brc = b_reset[c], bic = b_input[c];

    const int tile0 = blockIdx.x * TPB;
    float4 pf[16];
    {
        const float4* xb = (const float4*)(X + (size_t)tile0 * 64 * DIM_IN);
#pragma unroll
        for (int i = 0; i < 16; ++i) pf[i] = xb[tid + 256 * i];
    }

#pragma unroll 1
    for (int tI = 0; tI < TPB; ++tI) {
        // stage current tile to LDS (f32 -> f16)
#pragma unroll
        for (int i = 0; i < 16; ++i) {
            const int f   = tid + 256 * i;
            const int row = f >> 6;
            const int kq  = f & 63;
            const float4 v = pf[i];
            h2_t a, b2;
            a[0]  = (_Float16)v.x; a[1]  = (_Float16)v.y;
            b2[0] = (_Float16)v.z; b2[1] = (_Float16)v.w;
            _Float16* dst = &xs[row * LDK + kq * 4];
            *(h2_t*)dst = a; *(h2_t*)(dst + 2) = b2;
        }
        __syncthreads();
        // prefetch next tile (HBM latency hides under the MFMA phase)
        if (tI + 1 < TPB) {
            const float4* xb = (const float4*)(X + (size_t)(tile0 + tI + 1) * 64 * DIM_IN);
#pragma unroll
            for (int i = 0; i < 16; ++i) pf[i] = xb[tid + 256 * i];
        }
        const size_t orow0 = (size_t)(tile0 + tI) * 64;
#pragma unroll
        for (int rt = 0; rt < 4; ++rt) {
            const int r0 = rt * 16;
            f32x4 au = {0.f,0.f,0.f,0.f}, ar = {0.f,0.f,0.f,0.f}, aa = {0.f,0.f,0.f,0.f};
#pragma unroll
            for (int kt = 0; kt < 8; ++kt) {
                const h8_t a = *(const h8_t*)&xs[(r0 + m16) * LDK + kt * 32 + q * 8];
                au = __builtin_amdgcn_mfma_f32_16x16x32_f16(a, bu[kt],  au, 0, 0, 0);
                ar = __builtin_amdgcn_mfma_f32_16x16x32_f16(a, brf[kt], ar, 0, 0, 0);
                aa = __builtin_amdgcn_mfma_f32_16x16x32_f16(a, bif[kt], aa, 0, 0, 0);
            }
#pragma unroll
            for (int i = 0; i < 4; ++i) {
                const size_t grow = orow0 + r0 + q * 4 + i;
                h2_t pk;
                pk[0] = (_Float16)(-1.44269504f * (au[i] + bzc));
                pk[1] = (_Float16)(-1.44269504f * (ar[i] + brc));
                xur_out[grow * DIM_H + c] = __builtin_bit_cast(unsigned, pk);
                const float xiv = 2.88539008f * (aa[i] + bic);
                if (XI16) xi16_out[grow * DIM_H + c] = (_Float16)xiv;
                else      xi32_out[grow * DIM_H + c] = xiv;
            }
        }
        __syncthreads();
    }
}

// ---------------------------------------------------------------------------
// Pass 2: recurrence. R3 changes vs R2:
//  * NO lgkmcnt(0) fences. R1 ran fence-free and PASSED (identical absmax):
//    same-wave DS ops are processed in order by the LDS pipe, and the
//    compiler keeps program order via same-array may-alias. Removing the
//    fences lets the broadcast ds_reads issue back-to-back with the ds_write
//    instead of waiting for write retirement (~2 x 50 cyc/step).
//  * 8-accumulator dot trees on the critical-path r and i matvecs
//    (dependent-dot2 chain depth 8 -> 4).
//  * Uniform row-pointer addressing for the gate/out streams: row base is
//    wave-uniform (SGPR, stepped on the SALU), lane offset j rides in the
//    voffset -> strips the per-step 64-bit VGPR address math.
// ---------------------------------------------------------------------------

#define DOTR(HX, Q, A0, A1, A2, A3)                                 \
    A0 = dot2(HX.p[0], wr[4*(Q)+0], A0);                            \
    A1 = dot2(HX.p[1], wr[4*(Q)+1], A1);                            \
    A2 = dot2(HX.p[2], wr[4*(Q)+2], A2);                            \
    A3 = dot2(HX.p[3], wr[4*(Q)+3], A3);

#define DOTZ(HX, Q)                                                 \
    az0 = dot2(HX.p[0], wu[4*(Q)+0], az0);                          \
    az1 = dot2(HX.p[1], wu[4*(Q)+1], az1);                          \
    az2 = dot2(HX.p[2], wu[4*(Q)+2], az2);                          \
    az3 = dot2(HX.p[3], wu[4*(Q)+3], az3);

#define DOTI(SX, Q, A0, A1, A2, A3)                                 \
    A0 = dot2(SX.p[0], wi[4*(Q)+0], A0);                            \
    A1 = dot2(SX.p[1], wi[4*(Q)+1], A1);                            \
    A2 = dot2(SX.p[2], wi[4*(Q)+2], A2);                            \
    A3 = dot2(SX.p[3], wi[4*(Q)+3], A3);

template <int XI16>
__global__
__attribute__((amdgpu_flat_work_group_size(64, 64)))
__attribute__((amdgpu_waves_per_eu(1, 1)))
void gru_rec(const unsigned* __restrict__ xur, const _Float16* __restrict__ xi16,
             const float* xif,
             const float* __restrict__ W_input, const float* __restrict__ W_update,
             const float* __restrict__ W_reset,
             float* __restrict__ out)
{
    const int b = blockIdx.x;
    const int j = threadIdx.x;

    __shared__ __align__(16) _Float16 hh[DIM_H];
    __shared__ __align__(16) _Float16 ss[DIM_H];

    h2_t wu[32], wr[32], wi[32];
#pragma unroll
    for (int m = 0; m < 32; ++m) {
        const int k = DIM_IN + 2 * m;
        h2_t a, cc, d;
        a[0]  = (_Float16)W_update[(k    ) * DIM_H + j];
        a[1]  = (_Float16)W_update[(k + 1) * DIM_H + j];
        cc[0] = (_Float16)W_reset [(k    ) * DIM_H + j];
        cc[1] = (_Float16)W_reset [(k + 1) * DIM_H + j];
        d[0]  = (_Float16)W_input [(k    ) * DIM_H + j];
        d[1]  = (_Float16)W_input [(k + 1) * DIM_H + j];
        wu[m] = a; wr[m] = cc; wi[m] = d;
    }

    hh[j] = (_Float16)0.f;
    float hprev = 0.f;

    // Wave-uniform stream bases; lane offset j stays in the voffset so the
    // per-step advance is pure SALU.
    gcu32_p xb  = (gcu32_p)(xur  + (size_t)b * SEQ_LEN * DIM_H);
    gch16_p ib  = (gch16_p)(xi16 + (size_t)b * SEQ_LEN * DIM_H);
    gcf32_p ifb = (gcf32_p)(xif  + (size_t)b * SEQ_LEN * DIM_H);
    gf32_p  ob  = (gf32_p)(out  + (size_t)b * SEQ_LEN * DIM_H);

    unsigned ru[8];
    float    rxi[8];
#pragma unroll
    for (int d = 0; d < 8; ++d) {
        ru[d]  = xb[(size_t)d * DIM_H + j];
        rxi[d] = XI16 ? (float)ib[(size_t)d * DIM_H + j] : ifb[(size_t)d * DIM_H + j];
    }

#pragma unroll 1
    for (int tb = 0; tb < SEQ_LEN / 8; ++tb) {
#pragma unroll
        for (int u = 0; u < 8; ++u) {
            const int t = tb * 8 + u;
            // consume ring slot (loaded 8 steps ago), refill for t+8
            const h2_t pr = __builtin_bit_cast(h2_t, ru[u]);
            const float xu = (float)pr[0];
            const float xr = (float)pr[1];
            const float xi = rxi[u];
            const int tp = (t + 8 < SEQ_LEN) ? t + 8 : SEQ_LEN - 1;   // uniform
            ru[u]  = xb[(size_t)tp * DIM_H + j];
            rxi[u] = XI16 ? (float)ib[(size_t)tp * DIM_H + j]
                          : ifb[(size_t)tp * DIM_H + j];

            // broadcast-read h (8 x b128); no fence: same-wave DS in-order
            const H8* hp = (const H8*)hh;
            H8 hx0 = hp[0], hx1 = hp[1], hx2 = hp[2], hx3 = hp[3],
               hx4 = hp[4], hx5 = hp[5], hx6 = hp[6], hx7 = hp[7];

            // phase A: r-gate (8 accs, dep chain 4) -> ss write ASAP
            float ar0=0.f,ar1=0.f,ar2=0.f,ar3=0.f,ar4=0.f,ar5=0.f,ar6=0.f,ar7=0.f;
            DOTR(hx0,0, ar0,ar1,ar2,ar3) DOTR(hx1,1, ar4,ar5,ar6,ar7)
            DOTR(hx2,2, ar0,ar1,ar2,ar3) DOTR(hx3,3, ar4,ar5,ar6,ar7)
            DOTR(hx4,4, ar0,ar1,ar2,ar3) DOTR(hx5,5, ar4,ar5,ar6,ar7)
            DOTR(hx6,6, ar0,ar1,ar2,ar3) DOTR(hx7,7, ar4,ar5,ar6,ar7)
            const float drs = ((ar0 + ar4) + (ar1 + ar5)) + ((ar2 + ar6) + (ar3 + ar7));
            const float rg = rcp_(1.f + exp2_(fmaf(drs, -1.44269504f, xr)));
            ss[j] = (_Float16)(hprev * rg);

            // phase B: issue ss reads immediately (write->read ordered by the
            // in-order LDS pipe); hide their latency under the z dots
            const H8* sp = (const H8*)ss;
            H8 sx0 = sp[0], sx1 = sp[1], sx2 = sp[2], sx3 = sp[3],
               sx4 = sp[4], sx5 = sp[5], sx6 = sp[6], sx7 = sp[7];

            float az0 = 0.f, az1 = 0.f, az2 = 0.f, az3 = 0.f;
            DOTZ(hx0,0) DOTZ(hx1,1) DOTZ(hx2,2) DOTZ(hx3,3)
            DOTZ(hx4,4) DOTZ(hx5,5) DOTZ(hx6,6) DOTZ(hx7,7)
            const float zg = rcp_(1.f + exp2_(
                fmaf((az0 + az1) + (az2 + az3), -1.44269504f, xu)));

            // phase C: candidate (8 accs, dep chain 4)
            float ax0=0.f,ax1=0.f,ax2=0.f,ax3=0.f,ax4=0.f,ax5=0.f,ax6=0.f,ax7=0.f;
            DOTI(sx0,0, ax0,ax1,ax2,ax3) DOTI(sx1,1, ax4,ax5,ax6,ax7)
            DOTI(sx2,2, ax0,ax1,ax2,ax3) DOTI(sx3,3, ax4,ax5,ax6,ax7)
            DOTI(sx4,4, ax0,ax1,ax2,ax3) DOTI(sx5,5, ax4,ax5,ax6,ax7)
            DOTI(sx6,6, ax0,ax1,ax2,ax3) DOTI(sx7,7, ax4,ax5,ax6,ax7)
            const float dxs = ((ax0 + ax4) + (ax1 + ax5)) + ((ax2 + ax6) + (ax3 + ax7));
            const float th = fmaf(-2.f, rcp_(1.f + exp2_(
                fmaf(dxs, 2.88539008f, xi))), 1.f);

            const float hn = fmaf(zg, th - hprev, hprev);
            hh[j] = (_Float16)hn;                 // issue write, then...
            ob[(size_t)t * DIM_H + j] = hn;       // vm store in its shadow
            hprev = hn;
        }
    }
}

extern "C" void kernel_launch(void* const* d_in, const int* in_sizes, int n_in,
                              void* d_out, int out_size, void* d_ws, size_t ws_size,
                              hipStream_t stream) {
    const float* inputs   = (const float*)d_in[0];
    const float* W_input  = (const float*)d_in[1];
    const float* b_input  = (const float*)d_in[2];
    const float* W_update = (const float*)d_in[3];
    const float* b_update = (const float*)d_in[4];
    const float* W_reset  = (const float*)d_in[5];
    const float* b_reset  = (const float*)d_in[6];
    float* out = (float*)d_out;

    const int    batch = in_sizes[0] / (SEQ_LEN * DIM_IN);
    const size_t rows  = (size_t)batch * SEQ_LEN;
    const int    nblk  = (int)(rows / 64 / TPB);

    unsigned* xur_w = (unsigned*)d_ws;                       // rows*64*4 B
    _Float16* xi_w  = (_Float16*)(xur_w + rows * DIM_H);     // rows*64*2 B
    const bool xi16 = ws_size >= rows * DIM_H * 6ull;        // 50.3 MB (proven R3/R4)

    if (xi16) {
        gru_prepass_mfma<1><<<nblk, 256, 0, stream>>>(
            inputs, W_input, b_input, W_update, b_update, W_reset, b_reset,
            xur_w, xi_w, out);
        gru_rec<1><<<batch, 64, 0, stream>>>(xur_w, xi_w, out,
                                             W_input, W_update, W_reset, out);
    } else {
        // xi f32 lives in `out`: rec reads slot t+8 before it writes slot t
        gru_prepass_mfma<0><<<nblk, 256, 0, stream>>>(
            inputs, W_input, b_input, W_update, b_update, W_reset, b_reset,
            xur_w, xi_w, out);
        gru_rec<0><<<batch, 64, 0, stream>>>(xur_w, xi_w, out,
                                             W_input, W_update, W_reset, out);
    }
}